// Round 2
// baseline (502.125 us; speedup 1.0000x reference)
//
#include <hip/hip_runtime.h>
#include <hip/hip_bf16.h>

#define N_NODES 50000
#define N_EDGES 800000
#define D 128

// ---------------- CSR build (by dst) ----------------
// NOTE: harness passes integer inputs as int32 (adj_list int64 -> const int*).

__global__ void count_kernel(const int* __restrict__ adj, int* __restrict__ deg) {
    int e = blockIdx.x * blockDim.x + threadIdx.x;
    if (e < N_EDGES) {
        int d = adj[N_EDGES + e];
        atomicAdd(&deg[d], 1);
    }
}

__global__ void scan1_kernel(const int* __restrict__ deg, int* __restrict__ rowptr,
                             int* __restrict__ parts) {
    __shared__ int sm[256];
    int i = blockIdx.x * 256 + threadIdx.x;
    int v = (i < N_NODES) ? deg[i] : 0;
    sm[threadIdx.x] = v;
    __syncthreads();
    for (int off = 1; off < 256; off <<= 1) {
        int t = (threadIdx.x >= off) ? sm[threadIdx.x - off] : 0;
        __syncthreads();
        sm[threadIdx.x] += t;
        __syncthreads();
    }
    if (i < N_NODES) rowptr[i] = sm[threadIdx.x] - v;   // exclusive within block
    if (threadIdx.x == 255) parts[blockIdx.x] = sm[255];
}

__global__ void scan2_kernel(int* parts, int nb) {
    __shared__ int sm[256];
    int v = (threadIdx.x < nb) ? parts[threadIdx.x] : 0;
    sm[threadIdx.x] = v;
    __syncthreads();
    for (int off = 1; off < 256; off <<= 1) {
        int t = (threadIdx.x >= off) ? sm[threadIdx.x - off] : 0;
        __syncthreads();
        sm[threadIdx.x] += t;
        __syncthreads();
    }
    if (threadIdx.x < nb) parts[threadIdx.x] = sm[threadIdx.x] - v;  // exclusive
}

__global__ void scan3_kernel(int* __restrict__ rowptr, const int* __restrict__ parts,
                             int* __restrict__ cursor) {
    int i = blockIdx.x * 256 + threadIdx.x;
    if (i < N_NODES) {
        int v = rowptr[i] + parts[i >> 8];
        rowptr[i] = v;
        cursor[i] = v;
    }
    if (i == 0) rowptr[N_NODES] = N_EDGES;
}

__global__ void scatter_kernel(const int* __restrict__ adj, int* __restrict__ cursor,
                               int* __restrict__ ssrc) {
    int e = blockIdx.x * blockDim.x + threadIdx.x;
    if (e < N_EDGES) {
        int d = adj[N_EDGES + e];
        int p = atomicAdd(&cursor[d], 1);
        ssrc[p] = adj[e];
    }
}

// ---------------- GEMM: H = X @ W, fused AS = H@a_src, AD = H@a_dst ----------------
// block = 512 threads (8 waves), 64 rows/block, 8 rows/wave.
// lane l computes output cols {l, l+64}. W^T staged in LDS with pad 132
// (16B-aligned; stride mod 32 = 4 -> 8 bank groups on ds_read_b128).

__global__ __launch_bounds__(512) void gemm_kernel(
        const float* __restrict__ X, const float* __restrict__ W,
        const float* __restrict__ a_src, const float* __restrict__ a_dst,
        float* __restrict__ H, float* __restrict__ AS, float* __restrict__ AD) {
    __shared__ float wt[D * 132];     // W^T: wt[c*132 + k]
    __shared__ float xt[64 * D];      // x tile
    int tid = threadIdx.x;
    int row0 = blockIdx.x * 64;

    for (int i = tid; i < D * D; i += 512) {
        int k = i >> 7, c = i & 127;
        wt[c * 132 + k] = W[i];
    }
    for (int i = tid; i < 64 * D; i += 512) {
        int gr = row0 + (i >> 7);
        xt[i] = (gr < N_NODES) ? X[gr * D + (i & 127)] : 0.f;
    }
    __syncthreads();

    int wave = tid >> 6, l = tid & 63;
    int rbase = wave * 8;
    float acc[8][2];
#pragma unroll
    for (int j = 0; j < 8; ++j) { acc[j][0] = 0.f; acc[j][1] = 0.f; }

    const float4* wt0 = (const float4*)&wt[l * 132];
    const float4* wt1 = (const float4*)&wt[(l + 64) * 132];
#pragma unroll 4
    for (int t = 0; t < 32; ++t) {
        float4 w0 = wt0[t], w1 = wt1[t];
#pragma unroll
        for (int j = 0; j < 8; ++j) {
            float4 xv = *(const float4*)&xt[(rbase + j) * D + 4 * t];
            acc[j][0] += xv.x * w0.x + xv.y * w0.y + xv.z * w0.z + xv.w * w0.w;
            acc[j][1] += xv.x * w1.x + xv.y * w1.y + xv.z * w1.z + xv.w * w1.w;
        }
    }

    float as0 = a_src[l], as1 = a_src[l + 64];
    float ad0 = a_dst[l], ad1 = a_dst[l + 64];
#pragma unroll
    for (int j = 0; j < 8; ++j) {
        int gr = row0 + rbase + j;
        if (gr >= N_NODES) break;
        H[gr * D + l]      = acc[j][0];
        H[gr * D + 64 + l] = acc[j][1];
        float pa = acc[j][0] * as0 + acc[j][1] * as1;
        float pd = acc[j][0] * ad0 + acc[j][1] * ad1;
#pragma unroll
        for (int off = 32; off > 0; off >>= 1) {
            pa += __shfl_xor(pa, off);
            pd += __shfl_xor(pd, off);
        }
        if (l == 0) { AS[gr] = pa; AD[gr] = pd; }
    }
}

// ---------------- Aggregation: one wave per dst node ----------------
// out[dst] = (sum_e exp(leaky(as[src]+ad[dst])) * h[src]) / (sum_e exp(...) + 1e-16) + bias
// Softmax max-subtraction skipped: e = leaky(as+ad) is O(+-10) for this data,
// exp() stays in fp32 range, and exp(e)/sum exp(e) is exactly invariant.
// LAYER==1 additionally applies t = relu(0.1*x + 0.9*out).

template <int LAYER>
__global__ __launch_bounds__(256) void agg_kernel(
        const float* __restrict__ H, const float* __restrict__ AS, const float* __restrict__ AD,
        const int* __restrict__ rowptr, const int* __restrict__ ssrc,
        const float* __restrict__ bias, const float* __restrict__ Xskip,
        float* __restrict__ OUT) {
    int node = blockIdx.x * 4 + (threadIdx.x >> 6);
    if (node >= N_NODES) return;
    int l = threadIdx.x & 63;
    int e0 = rowptr[node], e1 = rowptr[node + 1];
    float adn = AD[node];
    float s = 0.f, acc0 = 0.f, acc1 = 0.f;
    for (int e = e0; e < e1; ++e) {
        int sn = ssrc[e];
        float w = AS[sn] + adn;
        w = (w > 0.f) ? w : 0.2f * w;   // leaky_relu 0.2
        w = __expf(w);
        s += w;
        const float* hp = H + sn * D;
        acc0 = fmaf(w, hp[l], acc0);
        acc1 = fmaf(w, hp[l + 64], acc1);
    }
    float inv = 1.f / (s + 1e-16f);
    float o0 = acc0 * inv + bias[l];
    float o1 = acc1 * inv + bias[l + 64];
    if (LAYER == 1) {
        o0 = fmaxf(0.1f * Xskip[node * D + l] + 0.9f * o0, 0.f);
        o1 = fmaxf(0.1f * Xskip[node * D + 64 + l] + 0.9f * o1, 0.f);
    }
    OUT[node * D + l]      = o0;
    OUT[node * D + 64 + l] = o1;
}

// ---------------- launcher ----------------

extern "C" void kernel_launch(void* const* d_in, const int* in_sizes, int n_in,
                              void* d_out, int out_size, void* d_ws, size_t ws_size,
                              hipStream_t stream) {
    const float* x   = (const float*)d_in[0];
    const int*   adj = (const int*)d_in[1];   // harness passes integers as int32
    // d_in[2] = edge_attr, ignored (edge_dim=None in reference)
    const float* W1  = (const float*)d_in[3];
    const float* as1 = (const float*)d_in[4];
    const float* ad1 = (const float*)d_in[5];
    const float* b1  = (const float*)d_in[6];
    const float* W2  = (const float*)d_in[7];
    const float* as2 = (const float*)d_in[8];
    const float* ad2 = (const float*)d_in[9];
    const float* b2  = (const float*)d_in[10];
    float* out = (float*)d_out;

    char* ws = (char*)d_ws;
    size_t off = 0;
    auto alloc = [&](size_t bytes) -> void* {
        void* p = ws + off;
        off = (off + bytes + 255) & ~(size_t)255;
        return p;
    };
    float* H      = (float*)alloc((size_t)N_NODES * D * 4);   // 25.6 MB
    float* AS     = (float*)alloc((size_t)N_NODES * 4);
    float* AD     = (float*)alloc((size_t)N_NODES * 4);
    int*   deg    = (int*)alloc((size_t)N_NODES * 4);
    int*   rowptr = (int*)alloc((size_t)(N_NODES + 1) * 4);
    int*   cursor = (int*)alloc((size_t)N_NODES * 4);
    int*   ssrc   = (int*)alloc((size_t)N_EDGES * 4);         // 3.2 MB
    int*   parts  = (int*)alloc(256 * 4);
    float* T      = out;   // layer-1 output lives in d_out; dead before final write

    const int EB = (N_EDGES + 255) / 256;
    const int NB = (N_NODES + 255) / 256;   // 196

    hipMemsetAsync(deg, 0, (size_t)N_NODES * 4, stream);
    count_kernel<<<EB, 256, 0, stream>>>(adj, deg);
    scan1_kernel<<<NB, 256, 0, stream>>>(deg, rowptr, parts);
    scan2_kernel<<<1, 256, 0, stream>>>(parts, NB);
    scan3_kernel<<<NB, 256, 0, stream>>>(rowptr, parts, cursor);
    scatter_kernel<<<EB, 256, 0, stream>>>(adj, cursor, ssrc);

    const int GB = (N_NODES + 63) / 64;     // 782
    const int AB = (N_NODES + 3) / 4;       // 12500

    // layer 1
    gemm_kernel<<<GB, 512, 0, stream>>>(x, W1, as1, ad1, H, AS, AD);
    agg_kernel<1><<<AB, 256, 0, stream>>>(H, AS, AD, rowptr, ssrc, b1, x, T);
    // layer 2
    gemm_kernel<<<GB, 512, 0, stream>>>(T, W2, as2, ad2, H, AS, AD);
    agg_kernel<2><<<AB, 256, 0, stream>>>(H, AS, AD, rowptr, ssrc, b2, nullptr, out);
}

// Round 3
// 453.782 us; speedup vs baseline: 1.1065x; 1.1065x over previous
//
#include <hip/hip_runtime.h>
#include <hip/hip_bf16.h>

#define N_NODES 50000
#define N_EDGES 800000
#define D 128

// ---------------- CSR build (by dst) ----------------
// Harness passes integer inputs as int32 (adj_list -> const int*).

__global__ void count_kernel(const int* __restrict__ adj, int* __restrict__ deg) {
    int e = blockIdx.x * blockDim.x + threadIdx.x;
    if (e < N_EDGES) {
        int d = adj[N_EDGES + e];
        atomicAdd(&deg[d], 1);
    }
}

__global__ void scan1_kernel(const int* __restrict__ deg, int* __restrict__ rowptr,
                             int* __restrict__ parts) {
    __shared__ int sm[256];
    int i = blockIdx.x * 256 + threadIdx.x;
    int v = (i < N_NODES) ? deg[i] : 0;
    sm[threadIdx.x] = v;
    __syncthreads();
    for (int off = 1; off < 256; off <<= 1) {
        int t = (threadIdx.x >= off) ? sm[threadIdx.x - off] : 0;
        __syncthreads();
        sm[threadIdx.x] += t;
        __syncthreads();
    }
    if (i < N_NODES) rowptr[i] = sm[threadIdx.x] - v;   // exclusive within block
    if (threadIdx.x == 255) parts[blockIdx.x] = sm[255];
}

__global__ void scan2_kernel(int* parts, int nb) {
    __shared__ int sm[256];
    int v = (threadIdx.x < nb) ? parts[threadIdx.x] : 0;
    sm[threadIdx.x] = v;
    __syncthreads();
    for (int off = 1; off < 256; off <<= 1) {
        int t = (threadIdx.x >= off) ? sm[threadIdx.x - off] : 0;
        __syncthreads();
        sm[threadIdx.x] += t;
        __syncthreads();
    }
    if (threadIdx.x < nb) parts[threadIdx.x] = sm[threadIdx.x] - v;  // exclusive
}

__global__ void scan3_kernel(int* __restrict__ rowptr, const int* __restrict__ parts,
                             int* __restrict__ cursor) {
    int i = blockIdx.x * 256 + threadIdx.x;
    if (i < N_NODES) {
        int v = rowptr[i] + parts[i >> 8];
        rowptr[i] = v;
        cursor[i] = v;
    }
    if (i == 0) rowptr[N_NODES] = N_EDGES;
}

__global__ void scatter_kernel(const int* __restrict__ adj, int* __restrict__ cursor,
                               int* __restrict__ ssrc, int* __restrict__ sdst) {
    int e = blockIdx.x * blockDim.x + threadIdx.x;
    if (e < N_EDGES) {
        int d = adj[N_EDGES + e];
        int p = atomicAdd(&cursor[d], 1);
        ssrc[p] = adj[e];
        sdst[p] = d;
    }
}

// ---------------- per-edge attention weight (CSR order) ----------------
// ew[p] = exp(leaky_relu(AS[src] + AD[dst])). AS/AD are 200 KB -> L2-resident.
// Softmax max-subtraction skipped: scores are O(+-10), exp stays in fp32 range,
// and exp(e)/sum exp(e) is invariant to the shift.

__global__ __launch_bounds__(256) void edgew_kernel(
        const int* __restrict__ ssrc, const int* __restrict__ sdst,
        const float* __restrict__ AS, const float* __restrict__ AD,
        float* __restrict__ ew) {
    int e = blockIdx.x * 256 + threadIdx.x;
    if (e < N_EDGES) {
        float v = AS[ssrc[e]] + AD[sdst[e]];
        v = (v > 0.f) ? v : 0.2f * v;   // leaky_relu 0.2
        ew[e] = __expf(v);
    }
}

// ---------------- GEMM: H = X @ W, fused AS = H@a_src, AD = H@a_dst ----------------
// 512 threads (8 waves), 64 rows/block, 8 rows/wave; lane l owns cols {2l, 2l+1}.
// W staged in LDS in natural row-major layout (64 KB exactly, no pad):
//   lane l reads ws_[k*128 + 2l] as b64 -> 2 lanes/bank -> conflict-free (m136).
// X rows read as wave-uniform global float4 (broadcast; L1/L2-served) -> no xt
// tile, LDS stays at 64 KB -> 2 blocks/CU (vs 1 before).

__global__ __launch_bounds__(512, 4) void gemm_kernel(
        const float* __restrict__ X, const float* __restrict__ W,
        const float* __restrict__ a_src, const float* __restrict__ a_dst,
        float* __restrict__ H, float* __restrict__ AS, float* __restrict__ AD) {
    __shared__ float ws_[D * D];      // 64 KB
    int tid = threadIdx.x;
    {
        const float4* Wv = (const float4*)W;
        float4* SV = (float4*)ws_;
        for (int i = tid; i < D * D / 4; i += 512) SV[i] = Wv[i];
    }
    __syncthreads();

    int wave = tid >> 6, l = tid & 63;
    int rbase = blockIdx.x * 64 + wave * 8;
    float2 acc[8];
#pragma unroll
    for (int j = 0; j < 8; ++j) acc[j] = make_float2(0.f, 0.f);

    const float2* wsp = (const float2*)ws_;  // wsp[k*64 + l] = W[k][2l..2l+1]

    for (int t = 0; t < 32; ++t) {
        float4 xv[8];
#pragma unroll
        for (int j = 0; j < 8; ++j) {
            int r = rbase + j; r = (r < N_NODES) ? r : (N_NODES - 1);  // clamp, no fault
            xv[j] = *(const float4*)&X[r * D + 4 * t];
        }
#pragma unroll
        for (int kk = 0; kk < 4; ++kk) {
            float2 wv = wsp[(4 * t + kk) * 64 + l];
#pragma unroll
            for (int j = 0; j < 8; ++j) {
                float xs = (kk == 0) ? xv[j].x : (kk == 1) ? xv[j].y
                          : (kk == 2) ? xv[j].z : xv[j].w;
                acc[j].x = fmaf(xs, wv.x, acc[j].x);
                acc[j].y = fmaf(xs, wv.y, acc[j].y);
            }
        }
    }

    float2 asv = ((const float2*)a_src)[l];
    float2 adv = ((const float2*)a_dst)[l];
#pragma unroll
    for (int j = 0; j < 8; ++j) {
        int r = rbase + j;
        if (r >= N_NODES) break;
        *(float2*)&H[r * D + 2 * l] = acc[j];
        float pa = acc[j].x * asv.x + acc[j].y * asv.y;
        float pd = acc[j].x * adv.x + acc[j].y * adv.y;
#pragma unroll
        for (int off = 32; off > 0; off >>= 1) {
            pa += __shfl_xor(pa, off);
            pd += __shfl_xor(pd, off);
        }
        if (l == 0) { AS[r] = pa; AD[r] = pd; }
    }
}

// ---------------- Aggregation: 2 waves per dst node, chunk-4 pipelined ----------------
// out[dst] = (sum_e ew[e] * h[src_e]) / (sum_e ew[e] + 1e-16) + bias
// block 256 = 4 waves = 2 nodes; each node's CSR range split in half between its
// 2 waves (halves serial chain, doubles MLP); chunk-4 batches 4 row-gathers in
// flight; lane l holds cols {2l, 2l+1} -> one b64 load per 512B row.
// LAYER==1 additionally applies t = relu(0.1*x + 0.9*out).

template <int LAYER>
__global__ __launch_bounds__(256, 8) void agg_kernel(
        const float* __restrict__ H, const float* __restrict__ ew,
        const int* __restrict__ rowptr, const int* __restrict__ ssrc,
        const float* __restrict__ bias, const float* __restrict__ Xskip,
        float* __restrict__ OUT) {
    int pair = threadIdx.x >> 7;            // 0/1: which node in block
    int sub  = (threadIdx.x >> 6) & 1;      // 0/1: which wave of the pair
    int l    = threadIdx.x & 63;
    int node = blockIdx.x * 2 + pair;       // N even: never OOB (25000*2)

    __shared__ float cacc[2][128];
    __shared__ float cs[2];

    int e0 = rowptr[node], e1 = rowptr[node + 1];
    int emid = (e0 + e1) >> 1;
    int lo = sub ? emid : e0;
    int hi = sub ? e1 : emid;

    float2 acc = make_float2(0.f, 0.f);
    float s = 0.f;

    while (lo + 4 <= hi) {
        int   sn[4]; float wg[4]; float2 hv[4];
#pragma unroll
        for (int i = 0; i < 4; ++i) { sn[i] = ssrc[lo + i]; wg[i] = ew[lo + i]; }
#pragma unroll
        for (int i = 0; i < 4; ++i) hv[i] = *(const float2*)&H[sn[i] * D + 2 * l];
#pragma unroll
        for (int i = 0; i < 4; ++i) {
            s += wg[i];
            acc.x = fmaf(wg[i], hv[i].x, acc.x);
            acc.y = fmaf(wg[i], hv[i].y, acc.y);
        }
        lo += 4;
    }
    for (; lo < hi; ++lo) {
        int sn = ssrc[lo]; float wg = ew[lo];
        float2 hv = *(const float2*)&H[sn * D + 2 * l];
        s += wg;
        acc.x = fmaf(wg, hv.x, acc.x);
        acc.y = fmaf(wg, hv.y, acc.y);
    }

    if (sub == 1) {
        cacc[pair][2 * l]     = acc.x;
        cacc[pair][2 * l + 1] = acc.y;
        if (l == 0) cs[pair] = s;
    }
    __syncthreads();
    if (sub == 0) {
        acc.x += cacc[pair][2 * l];
        acc.y += cacc[pair][2 * l + 1];
        s += cs[pair];
        float inv = 1.f / (s + 1e-16f);
        float2 bv = ((const float2*)bias)[l];
        float o0 = acc.x * inv + bv.x;
        float o1 = acc.y * inv + bv.y;
        if (LAYER == 1) {
            float2 xs = *(const float2*)&Xskip[node * D + 2 * l];
            o0 = fmaxf(0.1f * xs.x + 0.9f * o0, 0.f);
            o1 = fmaxf(0.1f * xs.y + 0.9f * o1, 0.f);
        }
        *(float2*)&OUT[node * D + 2 * l] = make_float2(o0, o1);
    }
}

// ---------------- launcher ----------------

extern "C" void kernel_launch(void* const* d_in, const int* in_sizes, int n_in,
                              void* d_out, int out_size, void* d_ws, size_t ws_size,
                              hipStream_t stream) {
    const float* x   = (const float*)d_in[0];
    const int*   adj = (const int*)d_in[1];   // int32 per harness contract
    // d_in[2] = edge_attr, ignored (edge_dim=None in reference)
    const float* W1  = (const float*)d_in[3];
    const float* as1 = (const float*)d_in[4];
    const float* ad1 = (const float*)d_in[5];
    const float* b1  = (const float*)d_in[6];
    const float* W2  = (const float*)d_in[7];
    const float* as2 = (const float*)d_in[8];
    const float* ad2 = (const float*)d_in[9];
    const float* b2  = (const float*)d_in[10];
    float* out = (float*)d_out;

    char* ws = (char*)d_ws;
    size_t off = 0;
    auto alloc = [&](size_t bytes) -> void* {
        void* p = ws + off;
        off = (off + bytes + 255) & ~(size_t)255;
        return p;
    };
    float* H      = (float*)alloc((size_t)N_NODES * D * 4);   // 25.6 MB
    float* AS     = (float*)alloc((size_t)N_NODES * 4);
    float* AD     = (float*)alloc((size_t)N_NODES * 4);
    int*   deg    = (int*)alloc((size_t)N_NODES * 4);
    int*   rowptr = (int*)alloc((size_t)(N_NODES + 1) * 4);
    int*   cursor = (int*)alloc((size_t)N_NODES * 4);
    int*   ssrc   = (int*)alloc((size_t)N_EDGES * 4);         // 3.2 MB
    int*   sdst   = (int*)alloc((size_t)N_EDGES * 4);         // 3.2 MB
    float* ew     = (float*)alloc((size_t)N_EDGES * 4);       // 3.2 MB
    int*   parts  = (int*)alloc(256 * 4);
    float* T      = out;   // layer-1 output lives in d_out; dead before final write

    const int EB = (N_EDGES + 255) / 256;
    const int NB = (N_NODES + 255) / 256;   // 196

    hipMemsetAsync(deg, 0, (size_t)N_NODES * 4, stream);
    count_kernel<<<EB, 256, 0, stream>>>(adj, deg);
    scan1_kernel<<<NB, 256, 0, stream>>>(deg, rowptr, parts);
    scan2_kernel<<<1, 256, 0, stream>>>(parts, NB);
    scan3_kernel<<<NB, 256, 0, stream>>>(rowptr, parts, cursor);
    scatter_kernel<<<EB, 256, 0, stream>>>(adj, cursor, ssrc, sdst);

    const int GB = (N_NODES + 63) / 64;     // 782
    const int AB = N_NODES / 2;             // 25000 (2 nodes/block)

    // layer 1
    gemm_kernel<<<GB, 512, 0, stream>>>(x, W1, as1, ad1, H, AS, AD);
    edgew_kernel<<<EB, 256, 0, stream>>>(ssrc, sdst, AS, AD, ew);
    agg_kernel<1><<<AB, 256, 0, stream>>>(H, ew, rowptr, ssrc, b1, x, T);
    // layer 2
    gemm_kernel<<<GB, 512, 0, stream>>>(T, W2, as2, ad2, H, AS, AD);
    edgew_kernel<<<EB, 256, 0, stream>>>(ssrc, sdst, AS, AD, ew);
    agg_kernel<2><<<AB, 256, 0, stream>>>(H, ew, rowptr, ssrc, b2, nullptr, out);
}